// Round 1
// baseline (1469.978 us; speedup 1.0000x reference)
//
#include <hip/hip_runtime.h>
#include <hip/hip_cooperative_groups.h>

namespace cg = cooperative_groups;

#define NPTS 16384
#define DIN  1024
#define DP   128
#define NS   163
#define NBLK 32          // cooperative blocks
#define BTHR 512         // threads per cooperative block

// ---------------- K1: projection GEMM  R[N,128] = F[N,1024] @ W[1024,128] (f32)
__global__ __launch_bounds__(256) void k_proj(const float* __restrict__ F,
                                              const float* __restrict__ W,
                                              float* __restrict__ R) {
    __shared__ float As[32][36];    // 32 rows x 32 k (+pad)
    __shared__ float Bs[32][128];   // 32 k x 128 cols
    const int tid = threadIdx.x;
    const int bm  = blockIdx.x;            // 512 blocks * 32 rows
    const int lr  = tid >> 3;              // A-load row 0..31
    const int lc  = (tid & 7) * 4;         // A-load k-offset
    const int bkr = tid >> 5;              // B-load kk base 0..7
    const int bc  = (tid & 31) * 4;        // B-load col
    const int rg  = tid >> 5;              // 0..7
    const int cg  = tid & 31;              // 0..31
    const int r0  = rg * 4;
    const int c0  = cg * 4;

    float acc[4][4];
    #pragma unroll
    for (int i = 0; i < 4; ++i)
        #pragma unroll
        for (int j = 0; j < 4; ++j) acc[i][j] = 0.0f;

    for (int k0 = 0; k0 < DIN; k0 += 32) {
        __syncthreads();
        // stage A tile
        *(float4*)&As[lr][lc] =
            *(const float4*)&F[(size_t)(bm * 32 + lr) * DIN + k0 + lc];
        // stage B tile
        #pragma unroll
        for (int p = 0; p < 4; ++p) {
            const int kk = bkr + p * 8;
            *(float4*)&Bs[kk][bc] = *(const float4*)&W[(size_t)(k0 + kk) * DP + bc];
        }
        __syncthreads();
        #pragma unroll
        for (int kk = 0; kk < 32; ++kk) {
            const float a0 = As[r0 + 0][kk];
            const float a1 = As[r0 + 1][kk];
            const float a2 = As[r0 + 2][kk];
            const float a3 = As[r0 + 3][kk];
            const float4 b = *(const float4*)&Bs[kk][c0];
            acc[0][0] += a0 * b.x; acc[0][1] += a0 * b.y; acc[0][2] += a0 * b.z; acc[0][3] += a0 * b.w;
            acc[1][0] += a1 * b.x; acc[1][1] += a1 * b.y; acc[1][2] += a1 * b.z; acc[1][3] += a1 * b.w;
            acc[2][0] += a2 * b.x; acc[2][1] += a2 * b.y; acc[2][2] += a2 * b.z; acc[2][3] += a2 * b.w;
            acc[3][0] += a3 * b.x; acc[3][1] += a3 * b.y; acc[3][2] += a3 * b.z; acc[3][3] += a3 * b.w;
        }
    }
    #pragma unroll
    for (int i = 0; i < 4; ++i) {
        float4 v = make_float4(acc[i][0], acc[i][1], acc[i][2], acc[i][3]);
        *(float4*)&R[(size_t)(bm * 32 + r0 + i) * DP + c0] = v;
    }
}

// ---------------- K2: per-row squared norm sq[i] = ||R_i||^2 (wave per row, fixed order)
__global__ void k_sq(const float* __restrict__ R, float* __restrict__ sq) {
    const int lane = threadIdx.x & 63;
    const int wave = (blockIdx.x * blockDim.x + threadIdx.x) >> 6;  // 0..255
    for (int row = wave; row < NPTS; row += 256) {
        const float a = R[(size_t)row * DP + lane];
        const float b = R[(size_t)row * DP + 64 + lane];
        float v = a * a + b * b;
        #pragma unroll
        for (int off = 32; off; off >>= 1) v += __shfl_xor(v, off);
        if (lane == 0) sq[row] = v;
    }
}

// ---------------- K3: column sums t[c] = sum_i R[i][c]; tS[128] = S = sum sq  (deterministic)
__global__ void k_colsum(const float* __restrict__ R, const float* __restrict__ sq,
                         float* __restrict__ tS) {
    __shared__ float s[256];
    const int b = blockIdx.x, tid = threadIdx.x;
    float v = 0.0f;
    if (b < DP) {
        for (int r = tid; r < NPTS; r += 256) v += R[(size_t)r * DP + b];
    } else {
        for (int r = tid; r < NPTS; r += 256) v += sq[r];
    }
    s[tid] = v;
    __syncthreads();
    for (int off = 128; off; off >>= 1) {
        if (tid < off) s[tid] += s[tid + off];
        __syncthreads();
    }
    if (tid == 0) tS[b] = s[0];
}

// ---------------- K4: cooperative greedy FPS loop + final gather
__global__ __launch_bounds__(BTHR, 2) void k_greedy(
    const float* __restrict__ R, const float* __restrict__ sq,
    const float* __restrict__ tS, const float* __restrict__ F,
    unsigned long long* gmax, unsigned int* idxlist, float* __restrict__ out) {
    cg::grid_group grid = cg::this_grid();
    __shared__ float rsel[DP];
    __shared__ unsigned long long wmax[BTHR / 64];

    const int tid  = threadIdx.x;
    const int lane = tid & 63;
    const int wid  = tid >> 6;
    const int g    = blockIdx.x * BTHR + tid;   // my point id, 0..16383

    // own projected row in registers (32 x float4 = 128 VGPRs)
    float4 rr[32];
    #pragma unroll
    for (int q = 0; q < 32; ++q) rr[q] = *(const float4*)&R[(size_t)g * DP + q * 4];
    const float sqi = sq[g];

    // anchor0 = sqrt(N*sq_i + S - 2*r_i.t)   (clip negligible; common terms don't affect ranking)
    float dott = 0.0f;
    #pragma unroll
    for (int q = 0; q < 32; ++q) {
        const float4 t4 = *(const float4*)&tS[q * 4];
        dott += rr[q].x * t4.x + rr[q].y * t4.y + rr[q].z * t4.z + rr[q].w * t4.w;
    }
    const float S = tS[DP];
    float anchor = sqrtf(fmaxf((float)NPTS * sqi + S - 2.0f * dott, 0.0f));

    for (int k = 0; k < NS; ++k) {
        // ---- argmax(anchor) with first-occurrence tie-break: key = (bits(anchor)<<32)|(~g)
        unsigned long long key =
            ((unsigned long long)__float_as_uint(anchor) << 32) |
            (unsigned long long)(0xFFFFFFFFu - (unsigned)g);
        #pragma unroll
        for (int off = 32; off; off >>= 1) {
            const unsigned long long o = __shfl_xor(key, off);
            key = (o > key) ? o : key;
        }
        if (lane == 0) wmax[wid] = key;
        __syncthreads();
        unsigned long long bk = wmax[0];
        #pragma unroll
        for (int w = 1; w < BTHR / 64; ++w) bk = (wmax[w] > bk) ? wmax[w] : bk;
        if (tid == 0)
            __hip_atomic_store(&gmax[k * NBLK + blockIdx.x], bk,
                               __ATOMIC_RELEASE, __HIP_MEMORY_SCOPE_AGENT);
        grid.sync();
        unsigned long long gk = 0;
        if (lane < NBLK)
            gk = __hip_atomic_load(&gmax[k * NBLK + lane],
                                   __ATOMIC_ACQUIRE, __HIP_MEMORY_SCOPE_AGENT);
        #pragma unroll
        for (int off = 32; off; off >>= 1) {
            const unsigned long long o = __shfl_xor(gk, off);
            gk = (o > gk) ? o : gk;
        }
        const unsigned idx = 0xFFFFFFFFu - (unsigned)(gk & 0xFFFFFFFFull);
        if (g == 0)
            __hip_atomic_store(&idxlist[k], idx, __ATOMIC_RELEASE, __HIP_MEMORY_SCOPE_AGENT);

        // ---- broadcast selected row, update anchor = min(anchor, dist(i, idx))
        if (tid < 32)
            *(float4*)&rsel[tid * 4] = *(const float4*)&R[(size_t)idx * DP + tid * 4];
        __syncthreads();
        const float sqs = sq[idx];
        float dot = 0.0f;
        #pragma unroll
        for (int q = 0; q < 32; ++q) {
            const float4 w4 = *(const float4*)&rsel[q * 4];
            dot += rr[q].x * w4.x + rr[q].y * w4.y + rr[q].z * w4.z + rr[q].w * w4.w;
        }
        const float d = sqrtf(fmaxf(sqi + sqs - 2.0f * dot, 0.0f));
        anchor = fminf(anchor, d);
    }

    grid.sync();
    // ---- gather output rows: out[k] = F[idx_k]
    for (int k = blockIdx.x; k < NS; k += NBLK) {
        const unsigned idx = __hip_atomic_load(&idxlist[k],
                                               __ATOMIC_ACQUIRE, __HIP_MEMORY_SCOPE_AGENT);
        if (tid < DIN / 4) {
            *(float4*)&out[(size_t)k * DIN + tid * 4] =
                *(const float4*)&F[(size_t)idx * DIN + tid * 4];
        }
    }
}

extern "C" void kernel_launch(void* const* d_in, const int* in_sizes, int n_in,
                              void* d_out, int out_size, void* d_ws, size_t ws_size,
                              hipStream_t stream) {
    const float* F = (const float*)d_in[0];   // [16384,1024]
    const float* W = (const float*)d_in[1];   // [1024,128]
    float* out = (float*)d_out;               // [163,1024]

    float* R  = (float*)d_ws;                 // 16384*128 f32 = 8 MiB
    float* sq = R + (size_t)NPTS * DP;        // 16384 f32
    float* tS = sq + NPTS;                    // 129 f32 (pad to 132)
    unsigned long long* gmax = (unsigned long long*)(tS + 132);  // NS*NBLK u64
    unsigned int* idxlist = (unsigned int*)(gmax + (size_t)NS * NBLK);

    hipLaunchKernelGGL(k_proj, dim3(NPTS / 32), dim3(256), 0, stream, F, W, R);
    hipLaunchKernelGGL(k_sq, dim3(64), dim3(256), 0, stream, R, sq);
    hipLaunchKernelGGL(k_colsum, dim3(DP + 1), dim3(256), 0, stream, R, sq, tS);

    const float* Rc = R; const float* sqc = sq; const float* tSc = tS; const float* Fc = F;
    unsigned long long* gm = gmax; unsigned int* il = idxlist; float* op = out;
    void* args[] = { (void*)&Rc, (void*)&sqc, (void*)&tSc, (void*)&Fc,
                     (void*)&gm, (void*)&il, (void*)&op };
    hipLaunchCooperativeKernel((const void*)k_greedy, dim3(NBLK), dim3(BTHR),
                               args, 0, stream);
}

// Round 2
// 1346.891 us; speedup vs baseline: 1.0914x; 1.0914x over previous
//
#include <hip/hip_runtime.h>

#define NPTS 16384
#define DIN  1024
#define DP   128
#define NS   163
#define NBLK 32          // cooperative blocks
#define BTHR 512         // threads per cooperative block
#define WPB  (BTHR / 64) // waves per block = 8
#define SLOTS (NBLK * WPB) // 256 wave slots per iteration

// ---------------- K1: projection GEMM  R[N,128] = F[N,1024] @ W[1024,128] (f32)
__global__ __launch_bounds__(256) void k_proj(const float* __restrict__ F,
                                              const float* __restrict__ W,
                                              float* __restrict__ R) {
    __shared__ float As[32][36];    // 32 rows x 32 k (+pad)
    __shared__ float Bs[32][128];   // 32 k x 128 cols
    const int tid = threadIdx.x;
    const int bm  = blockIdx.x;            // 512 blocks * 32 rows
    const int lr  = tid >> 3;              // A-load row 0..31
    const int lc  = (tid & 7) * 4;         // A-load k-offset
    const int bkr = tid >> 5;              // B-load kk base 0..7
    const int bc  = (tid & 31) * 4;        // B-load col
    const int rg  = tid >> 5;              // 0..7
    const int cg  = tid & 31;              // 0..31
    const int r0  = rg * 4;
    const int c0  = cg * 4;

    float acc[4][4];
    #pragma unroll
    for (int i = 0; i < 4; ++i)
        #pragma unroll
        for (int j = 0; j < 4; ++j) acc[i][j] = 0.0f;

    for (int k0 = 0; k0 < DIN; k0 += 32) {
        __syncthreads();
        *(float4*)&As[lr][lc] =
            *(const float4*)&F[(size_t)(bm * 32 + lr) * DIN + k0 + lc];
        #pragma unroll
        for (int p = 0; p < 4; ++p) {
            const int kk = bkr + p * 8;
            *(float4*)&Bs[kk][bc] = *(const float4*)&W[(size_t)(k0 + kk) * DP + bc];
        }
        __syncthreads();
        #pragma unroll
        for (int kk = 0; kk < 32; ++kk) {
            const float a0 = As[r0 + 0][kk];
            const float a1 = As[r0 + 1][kk];
            const float a2 = As[r0 + 2][kk];
            const float a3 = As[r0 + 3][kk];
            const float4 b = *(const float4*)&Bs[kk][c0];
            acc[0][0] += a0 * b.x; acc[0][1] += a0 * b.y; acc[0][2] += a0 * b.z; acc[0][3] += a0 * b.w;
            acc[1][0] += a1 * b.x; acc[1][1] += a1 * b.y; acc[1][2] += a1 * b.z; acc[1][3] += a1 * b.w;
            acc[2][0] += a2 * b.x; acc[2][1] += a2 * b.y; acc[2][2] += a2 * b.z; acc[2][3] += a2 * b.w;
            acc[3][0] += a3 * b.x; acc[3][1] += a3 * b.y; acc[3][2] += a3 * b.z; acc[3][3] += a3 * b.w;
        }
    }
    #pragma unroll
    for (int i = 0; i < 4; ++i) {
        float4 v = make_float4(acc[i][0], acc[i][1], acc[i][2], acc[i][3]);
        *(float4*)&R[(size_t)(bm * 32 + r0 + i) * DP + c0] = v;
    }
}

// ---------------- K2: per-row squared norm sq[i] = ||R_i||^2 (wave per row, fixed order)
__global__ void k_sq(const float* __restrict__ R, float* __restrict__ sq) {
    const int lane = threadIdx.x & 63;
    const int wave = (blockIdx.x * blockDim.x + threadIdx.x) >> 6;  // 0..255
    for (int row = wave; row < NPTS; row += 256) {
        const float a = R[(size_t)row * DP + lane];
        const float b = R[(size_t)row * DP + 64 + lane];
        float v = a * a + b * b;
        #pragma unroll
        for (int off = 32; off; off >>= 1) v += __shfl_xor(v, off);
        if (lane == 0) sq[row] = v;
    }
}

// ---------------- K3: column sums t[c] = sum_i R[i][c]; tS[128] = S = sum sq
__global__ void k_colsum(const float* __restrict__ R, const float* __restrict__ sq,
                         float* __restrict__ tS) {
    __shared__ float s[256];
    const int b = blockIdx.x, tid = threadIdx.x;
    float v = 0.0f;
    if (b < DP) {
        for (int r = tid; r < NPTS; r += 256) v += R[(size_t)r * DP + b];
    } else {
        for (int r = tid; r < NPTS; r += 256) v += sq[r];
    }
    s[tid] = v;
    __syncthreads();
    for (int off = 128; off; off >>= 1) {
        if (tid < off) s[tid] += s[tid + off];
        __syncthreads();
    }
    if (tid == 0) tS[b] = s[0];
}

// ---------------- K4: greedy FPS loop, data-as-barrier across 256 waves
__global__ __launch_bounds__(BTHR, 2) void k_greedy(
    const float* __restrict__ R, const float* __restrict__ sq,
    const float* __restrict__ tS, const float* __restrict__ F,
    unsigned long long* gmax, float* __restrict__ out) {
    __shared__ unsigned sidx[8];

    const int tid  = threadIdx.x;
    const int lane = tid & 63;
    const int wid  = tid >> 6;
    const int bid  = blockIdx.x;
    const int gw   = bid * WPB + wid;           // global wave id 0..255
    const int g    = bid * BTHR + tid;          // my point id, 0..16383

    // own projected row in registers (32 x float4 = 128 VGPRs), pinned
    float4 rr[32];
    #pragma unroll
    for (int q = 0; q < 32; ++q) rr[q] = *(const float4*)&R[(size_t)g * DP + q * 4];
    #pragma unroll
    for (int q = 0; q < 32; ++q)
        asm volatile("" : "+v"(rr[q].x), "+v"(rr[q].y), "+v"(rr[q].z), "+v"(rr[q].w));
    const float sqi = sq[g];

    // anchor0 = sqrt(N*sq_i + S - 2*r_i.t)  (common terms preserve ranking)
    float dott = 0.0f;
    #pragma unroll
    for (int q = 0; q < 32; ++q) {
        const float4 t4 = *(const float4*)&tS[q * 4];
        dott += rr[q].x * t4.x + rr[q].y * t4.y + rr[q].z * t4.z + rr[q].w * t4.w;
    }
    const float S = tS[DP];
    float anchor = sqrtf(fmaxf((float)NPTS * sqi + S - 2.0f * dott, 0.0f));

    for (int k = 0; k < NS; ++k) {
        // key = (bits(anchor)<<32) | (~g): max-key == first-occurrence argmax; never 0
        unsigned long long key =
            ((unsigned long long)__float_as_uint(anchor) << 32) |
            (unsigned long long)(0xFFFFFFFFu - (unsigned)g);
        #pragma unroll
        for (int off = 32; off; off >>= 1) {
            const unsigned long long o = __shfl_xor(key, off);
            key = (o > key) ? o : key;
        }
        if (lane == 0)
            __hip_atomic_store(&gmax[(size_t)k * SLOTS + gw], key,
                               __ATOMIC_RELAXED, __HIP_MEMORY_SCOPE_AGENT);

        // spin until all 256 wave slots for this iteration are published
        const unsigned long long* gs = &gmax[(size_t)k * SLOTS];
        unsigned long long v0, v1, v2, v3;
        do {
            v0 = __hip_atomic_load(&gs[lane      ], __ATOMIC_RELAXED, __HIP_MEMORY_SCOPE_AGENT);
            v1 = __hip_atomic_load(&gs[lane +  64], __ATOMIC_RELAXED, __HIP_MEMORY_SCOPE_AGENT);
            v2 = __hip_atomic_load(&gs[lane + 128], __ATOMIC_RELAXED, __HIP_MEMORY_SCOPE_AGENT);
            v3 = __hip_atomic_load(&gs[lane + 192], __ATOMIC_RELAXED, __HIP_MEMORY_SCOPE_AGENT);
        } while (!__all((v0 != 0ull) & (v1 != 0ull) & (v2 != 0ull) & (v3 != 0ull)));

        unsigned long long m = v0;
        if (v1 > m) m = v1;
        if (v2 > m) m = v2;
        if (v3 > m) m = v3;
        #pragma unroll
        for (int off = 32; off; off >>= 1) {
            const unsigned long long o = __shfl_xor(m, off);
            m = (o > m) ? o : m;
        }
        const unsigned idx = 0xFFFFFFFFu - (unsigned)(m & 0xFFFFFFFFull);
        if (tid == 0 && (k & 31) == bid) sidx[k >> 5] = idx;

        // anchor = min(anchor, dist(g, idx)); selected row via L1-broadcast loads
        const float sqs = sq[idx];
        const float* rs = &R[(size_t)idx * DP];
        float dot = 0.0f;
        #pragma unroll
        for (int q = 0; q < 32; ++q) {
            const float4 w4 = *(const float4*)&rs[q * 4];
            dot += rr[q].x * w4.x + rr[q].y * w4.y + rr[q].z * w4.z + rr[q].w * w4.w;
        }
        const float d = sqrtf(fmaxf(sqi + sqs - 2.0f * dot, 0.0f));
        anchor = fminf(anchor, d);
    }

    __syncthreads();
    // gather: block b owns k = b, b+32, ... (indices recorded in sidx)
    #pragma unroll
    for (int q = 0; q < 6; ++q) {
        const int k = q * 32 + bid;
        if (k >= NS) break;
        const unsigned idx = sidx[q];
        if (tid < DIN / 4) {
            *(float4*)&out[(size_t)k * DIN + tid * 4] =
                *(const float4*)&F[(size_t)idx * DIN + tid * 4];
        }
    }
}

extern "C" void kernel_launch(void* const* d_in, const int* in_sizes, int n_in,
                              void* d_out, int out_size, void* d_ws, size_t ws_size,
                              hipStream_t stream) {
    const float* F = (const float*)d_in[0];   // [16384,1024]
    const float* W = (const float*)d_in[1];   // [1024,128]
    float* out = (float*)d_out;               // [163,1024]

    float* R  = (float*)d_ws;                 // 16384*128 f32 = 8 MiB
    float* sq = R + (size_t)NPTS * DP;        // 16384 f32
    float* tS = sq + NPTS;                    // 129 f32 (pad to 132)
    unsigned long long* gmax = (unsigned long long*)(tS + 132);  // NS*SLOTS u64

    hipLaunchKernelGGL(k_proj, dim3(NPTS / 32), dim3(256), 0, stream, F, W, R);
    hipLaunchKernelGGL(k_sq, dim3(64), dim3(256), 0, stream, R, sq);
    hipLaunchKernelGGL(k_colsum, dim3(DP + 1), dim3(256), 0, stream, R, sq, tS);

    // slots must be zero at the start of EVERY call (graph replays don't re-poison)
    hipMemsetAsync(gmax, 0, (size_t)NS * SLOTS * sizeof(unsigned long long), stream);

    const float* Rc = R; const float* sqc = sq; const float* tSc = tS; const float* Fc = F;
    unsigned long long* gm = gmax; float* op = out;
    void* args[] = { (void*)&Rc, (void*)&sqc, (void*)&tSc, (void*)&Fc,
                     (void*)&gm, (void*)&op };
    hipLaunchCooperativeKernel((const void*)k_greedy, dim3(NBLK), dim3(BTHR),
                               args, 0, stream);
}

// Round 3
// 891.524 us; speedup vs baseline: 1.6488x; 1.5108x over previous
//
#include <hip/hip_runtime.h>

#define NPTS 16384
#define DIN  1024
#define DP   128
#define NS   163
#define NBLK 64          // cooperative blocks (1 per CU, 64 CUs active)
#define BTHR 256         // threads per block -> NBLK*BTHR = NPTS, 1 point/thread
#define WPB  (BTHR / 64) // waves per block = 4

// ---------------- K1: projection GEMM  R[N,128] = F[N,1024] @ W[1024,128] (f32)
__global__ __launch_bounds__(256) void k_proj(const float* __restrict__ F,
                                              const float* __restrict__ W,
                                              float* __restrict__ R) {
    __shared__ float As[32][36];    // 32 rows x 32 k (+pad)
    __shared__ float Bs[32][128];   // 32 k x 128 cols
    const int tid = threadIdx.x;
    const int bm  = blockIdx.x;            // 512 blocks * 32 rows
    const int lr  = tid >> 3;              // A-load row 0..31
    const int lc  = (tid & 7) * 4;         // A-load k-offset
    const int bkr = tid >> 5;              // B-load kk base 0..7
    const int bc  = (tid & 31) * 4;        // B-load col
    const int rg  = tid >> 5;              // 0..7
    const int cg  = tid & 31;              // 0..31
    const int r0  = rg * 4;
    const int c0  = cg * 4;

    float acc[4][4];
    #pragma unroll
    for (int i = 0; i < 4; ++i)
        #pragma unroll
        for (int j = 0; j < 4; ++j) acc[i][j] = 0.0f;

    for (int k0 = 0; k0 < DIN; k0 += 32) {
        __syncthreads();
        *(float4*)&As[lr][lc] =
            *(const float4*)&F[(size_t)(bm * 32 + lr) * DIN + k0 + lc];
        #pragma unroll
        for (int p = 0; p < 4; ++p) {
            const int kk = bkr + p * 8;
            *(float4*)&Bs[kk][bc] = *(const float4*)&W[(size_t)(k0 + kk) * DP + bc];
        }
        __syncthreads();
        #pragma unroll
        for (int kk = 0; kk < 32; ++kk) {
            const float a0 = As[r0 + 0][kk];
            const float a1 = As[r0 + 1][kk];
            const float a2 = As[r0 + 2][kk];
            const float a3 = As[r0 + 3][kk];
            const float4 b = *(const float4*)&Bs[kk][c0];
            acc[0][0] += a0 * b.x; acc[0][1] += a0 * b.y; acc[0][2] += a0 * b.z; acc[0][3] += a0 * b.w;
            acc[1][0] += a1 * b.x; acc[1][1] += a1 * b.y; acc[1][2] += a1 * b.z; acc[1][3] += a1 * b.w;
            acc[2][0] += a2 * b.x; acc[2][1] += a2 * b.y; acc[2][2] += a2 * b.z; acc[2][3] += a2 * b.w;
            acc[3][0] += a3 * b.x; acc[3][1] += a3 * b.y; acc[3][2] += a3 * b.z; acc[3][3] += a3 * b.w;
        }
    }
    #pragma unroll
    for (int i = 0; i < 4; ++i) {
        float4 v = make_float4(acc[i][0], acc[i][1], acc[i][2], acc[i][3]);
        *(float4*)&R[(size_t)(bm * 32 + r0 + i) * DP + c0] = v;
    }
}

// ---------------- K2: per-row squared norm sq[i] = ||R_i||^2 (wave per row)
__global__ void k_sq(const float* __restrict__ R, float* __restrict__ sq) {
    const int lane = threadIdx.x & 63;
    const int wave = (blockIdx.x * blockDim.x + threadIdx.x) >> 6;  // 0..255
    for (int row = wave; row < NPTS; row += 256) {
        const float a = R[(size_t)row * DP + lane];
        const float b = R[(size_t)row * DP + 64 + lane];
        float v = a * a + b * b;
        #pragma unroll
        for (int off = 32; off; off >>= 1) v += __shfl_xor(v, off);
        if (lane == 0) sq[row] = v;
    }
}

// ---------------- K3: column sums t[c] = sum_i R[i][c]; tS[128] = S = sum sq
__global__ void k_colsum(const float* __restrict__ R, const float* __restrict__ sq,
                         float* __restrict__ tS) {
    __shared__ float s[256];
    const int b = blockIdx.x, tid = threadIdx.x;
    float v = 0.0f;
    if (b < DP) {
        for (int r = tid; r < NPTS; r += 256) v += R[(size_t)r * DP + b];
    } else {
        for (int r = tid; r < NPTS; r += 256) v += sq[r];
    }
    s[tid] = v;
    __syncthreads();
    for (int off = 128; off; off >>= 1) {
        if (tid < off) s[tid] += s[tid + off];
        __syncthreads();
    }
    if (tid == 0) tS[b] = s[0];
}

// ---------------- K4: greedy FPS loop; 1 slot/block, single-load poll
__global__ __launch_bounds__(BTHR, 1) void k_greedy(
    const float* __restrict__ R, const float* __restrict__ sq,
    const float* __restrict__ tS, const float* __restrict__ F,
    unsigned long long* gmax, float* __restrict__ out) {
    __shared__ unsigned long long lmax[WPB];
    __shared__ unsigned sidx[(NS + NBLK - 1) / NBLK];   // 3

    const int tid  = threadIdx.x;
    const int lane = tid & 63;
    const int wid  = tid >> 6;
    const int bid  = blockIdx.x;
    const int g    = bid * BTHR + tid;          // my point id, 0..16383

    // own projected row in registers (32 x float4 = 128 VGPRs); launch_bounds(.,1)
    // lifts the VGPR cap to 512 so this cannot spill
    float4 rr[32];
    #pragma unroll
    for (int q = 0; q < 32; ++q) rr[q] = *(const float4*)&R[(size_t)g * DP + q * 4];
    #pragma unroll
    for (int q = 0; q < 32; ++q)
        asm volatile("" : "+v"(rr[q].x), "+v"(rr[q].y), "+v"(rr[q].z), "+v"(rr[q].w));
    const float sqi = sq[g];

    // anchor0 = sqrt(N*sq_i + S - 2*r_i.t)  (common terms preserve ranking)
    float a0 = 0.f, a1 = 0.f, a2 = 0.f, a3 = 0.f;
    #pragma unroll
    for (int q = 0; q < 32; ++q) {
        const float4 t4 = *(const float4*)&tS[q * 4];
        a0 += rr[q].x * t4.x; a1 += rr[q].y * t4.y;
        a2 += rr[q].z * t4.z; a3 += rr[q].w * t4.w;
    }
    const float S = tS[DP];
    float anchor = sqrtf(fmaxf((float)NPTS * sqi + S - 2.0f * ((a0 + a1) + (a2 + a3)), 0.0f));

    for (int k = 0; k < NS; ++k) {
        // key = (bits(anchor)<<32) | (~g): max-key == first-occurrence argmax; never 0
        unsigned long long key =
            ((unsigned long long)__float_as_uint(anchor) << 32) |
            (unsigned long long)(0xFFFFFFFFu - (unsigned)g);
        #pragma unroll
        for (int off = 32; off; off >>= 1) {
            const unsigned long long o = __shfl_xor(key, off);
            key = (o > key) ? o : key;
        }
        if (lane == 0) lmax[wid] = key;
        __syncthreads();
        if (tid == 0) {
            unsigned long long bk = lmax[0];
            #pragma unroll
            for (int w = 1; w < WPB; ++w) bk = (lmax[w] > bk) ? lmax[w] : bk;
            // store value depends on lmax reads -> any observer of this store
            // knows the lmax reads are done (safe LDS reuse next iteration)
            __hip_atomic_store(&gmax[(size_t)k * NBLK + bid], bk,
                               __ATOMIC_RELAXED, __HIP_MEMORY_SCOPE_AGENT);
        }

        // poll: one 8B load per lane covers all 64 block slots
        const unsigned long long* gs = &gmax[(size_t)k * NBLK];
        unsigned long long v;
        do {
            v = __hip_atomic_load(&gs[lane], __ATOMIC_RELAXED, __HIP_MEMORY_SCOPE_AGENT);
        } while (!__all(v != 0ull));

        #pragma unroll
        for (int off = 32; off; off >>= 1) {
            const unsigned long long o = __shfl_xor(v, off);
            v = (o > v) ? o : v;
        }
        const unsigned idx = 0xFFFFFFFFu - (unsigned)(v & 0xFFFFFFFFull);
        if (tid == 0 && (k & 63) == bid) sidx[k >> 6] = idx;

        // anchor = min(anchor, dist(g, idx)); selected row via L1-broadcast loads
        const float sqs = sq[idx];
        const float* rs = &R[(size_t)idx * DP];
        float d0 = 0.f, d1 = 0.f, d2 = 0.f, d3 = 0.f;
        #pragma unroll
        for (int q = 0; q < 32; ++q) {
            const float4 w4 = *(const float4*)&rs[q * 4];
            d0 += rr[q].x * w4.x; d1 += rr[q].y * w4.y;
            d2 += rr[q].z * w4.z; d3 += rr[q].w * w4.w;
        }
        const float d = sqrtf(fmaxf(sqi + sqs - 2.0f * ((d0 + d1) + (d2 + d3)), 0.0f));
        anchor = fminf(anchor, d);
    }

    __syncthreads();
    // gather: block b owns k = b, b+64, b+128 (indices recorded in sidx)
    #pragma unroll
    for (int q = 0; q < 3; ++q) {
        const int k = q * NBLK + bid;
        if (k < NS) {
            const unsigned idx = sidx[q];
            *(float4*)&out[(size_t)k * DIN + tid * 4] =
                *(const float4*)&F[(size_t)idx * DIN + tid * 4];
        }
    }
}

extern "C" void kernel_launch(void* const* d_in, const int* in_sizes, int n_in,
                              void* d_out, int out_size, void* d_ws, size_t ws_size,
                              hipStream_t stream) {
    const float* F = (const float*)d_in[0];   // [16384,1024]
    const float* W = (const float*)d_in[1];   // [1024,128]
    float* out = (float*)d_out;               // [163,1024]

    float* R  = (float*)d_ws;                 // 16384*128 f32 = 8 MiB
    float* sq = R + (size_t)NPTS * DP;        // 16384 f32
    float* tS = sq + NPTS;                    // 129 f32 (pad to 132)
    unsigned long long* gmax = (unsigned long long*)(tS + 132);  // NS*NBLK u64

    hipLaunchKernelGGL(k_proj, dim3(NPTS / 32), dim3(256), 0, stream, F, W, R);
    hipLaunchKernelGGL(k_sq, dim3(64), dim3(256), 0, stream, R, sq);
    hipLaunchKernelGGL(k_colsum, dim3(DP + 1), dim3(256), 0, stream, R, sq, tS);

    // slots must be zero at the start of EVERY call (graph replays don't re-poison)
    hipMemsetAsync(gmax, 0, (size_t)NS * NBLK * sizeof(unsigned long long), stream);

    const float* Rc = R; const float* sqc = sq; const float* tSc = tS; const float* Fc = F;
    unsigned long long* gm = gmax; float* op = out;
    void* args[] = { (void*)&Rc, (void*)&sqc, (void*)&tSc, (void*)&Fc,
                     (void*)&gm, (void*)&op };
    hipLaunchCooperativeKernel((const void*)k_greedy, dim3(NBLK), dim3(BTHR),
                               args, 0, stream);
}

// Round 4
// 731.099 us; speedup vs baseline: 2.0106x; 1.2194x over previous
//
#include <hip/hip_runtime.h>

#define NPTS 16384
#define DIN  1024
#define DP   128
#define NS   163
#define NBLK 64          // cooperative blocks (1 per CU)
#define BTHR 256         // threads per block -> NBLK*BTHR = NPTS, 1 point/thread
#define WPB  (BTHR / 64) // waves per block = 4

// ---------------- K1: projection GEMM  R[N,128] = F[N,1024] @ W[1024,128] (f32)
// 4-kk inner steps: A read as ds_read_b128 -> VALU-bound instead of LDS-bound
__global__ __launch_bounds__(256) void k_proj(const float* __restrict__ F,
                                              const float* __restrict__ W,
                                              float* __restrict__ R) {
    __shared__ float As[32][36];    // 32 rows x 32 k (+pad, 36 keeps 16B align)
    __shared__ float Bs[32][128];   // 32 k x 128 cols
    const int tid = threadIdx.x;
    const int bm  = blockIdx.x;            // 512 blocks * 32 rows
    const int lr  = tid >> 3;              // A-load row 0..31
    const int lc  = (tid & 7) * 4;         // A-load k-offset
    const int bkr = tid >> 5;              // B-load kk base 0..7
    const int bc  = (tid & 31) * 4;        // B-load col
    const int r0  = (tid >> 5) * 4;        // 0,4,..,28
    const int c0  = (tid & 31) * 4;        // 0,4,..,124

    float acc[4][4] = {};

    for (int k0 = 0; k0 < DIN; k0 += 32) {
        __syncthreads();
        *(float4*)&As[lr][lc] =
            *(const float4*)&F[(size_t)(bm * 32 + lr) * DIN + k0 + lc];
        #pragma unroll
        for (int p = 0; p < 4; ++p) {
            const int kk = bkr + p * 8;
            *(float4*)&Bs[kk][bc] = *(const float4*)&W[(size_t)(k0 + kk) * DP + bc];
        }
        __syncthreads();
        #pragma unroll
        for (int kt = 0; kt < 32; kt += 4) {
            float4 a[4], b[4];
            #pragma unroll
            for (int i = 0; i < 4; ++i) a[i] = *(const float4*)&As[r0 + i][kt];
            #pragma unroll
            for (int j = 0; j < 4; ++j) b[j] = *(const float4*)&Bs[kt + j][c0];
            #pragma unroll
            for (int i = 0; i < 4; ++i) {
                acc[i][0] += a[i].x * b[0].x; acc[i][1] += a[i].x * b[0].y;
                acc[i][2] += a[i].x * b[0].z; acc[i][3] += a[i].x * b[0].w;
                acc[i][0] += a[i].y * b[1].x; acc[i][1] += a[i].y * b[1].y;
                acc[i][2] += a[i].y * b[1].z; acc[i][3] += a[i].y * b[1].w;
                acc[i][0] += a[i].z * b[2].x; acc[i][1] += a[i].z * b[2].y;
                acc[i][2] += a[i].z * b[2].z; acc[i][3] += a[i].z * b[2].w;
                acc[i][0] += a[i].w * b[3].x; acc[i][1] += a[i].w * b[3].y;
                acc[i][2] += a[i].w * b[3].z; acc[i][3] += a[i].w * b[3].w;
            }
        }
    }
    #pragma unroll
    for (int i = 0; i < 4; ++i) {
        float4 v = make_float4(acc[i][0], acc[i][1], acc[i][2], acc[i][3]);
        *(float4*)&R[(size_t)(bm * 32 + r0 + i) * DP + c0] = v;
    }
}

// ---------------- K2: per-row squared norm sq[i] = ||R_i||^2 (wave per row)
__global__ void k_sq(const float* __restrict__ R, float* __restrict__ sq) {
    const int lane = threadIdx.x & 63;
    const int wave = (blockIdx.x * blockDim.x + threadIdx.x) >> 6;  // 0..255
    for (int row = wave; row < NPTS; row += 256) {
        const float a = R[(size_t)row * DP + lane];
        const float b = R[(size_t)row * DP + 64 + lane];
        float v = a * a + b * b;
        #pragma unroll
        for (int off = 32; off; off >>= 1) v += __shfl_xor(v, off);
        if (lane == 0) sq[row] = v;
    }
}

// ---------------- K3a: coalesced partial col sums over 256-row slabs; also clears gmax
__global__ __launch_bounds__(256) void k_colpart(const float* __restrict__ R,
                                                 const float* __restrict__ sq,
                                                 float* __restrict__ part,
                                                 float* __restrict__ part_sq,
                                                 unsigned long long* __restrict__ gmax) {
    const int b = blockIdx.x, tid = threadIdx.x;

    // clear the greedy slots (64 blocks x 256 threads = 16384 >= NS*NBLK)
    const int slot = b * 256 + tid;
    if (slot < NS * NBLK) gmax[slot] = 0ull;

    if (tid < DP) {
        float acc = 0.0f;
        const float* p = R + (size_t)b * 256 * DP + tid;
        #pragma unroll 8
        for (int r = 0; r < 256; ++r) acc += p[(size_t)r * DP];
        part[b * DP + tid] = acc;
    } else if (tid < 192) {
        const int lane = tid - 128;   // wave 2: partial sum of sq over the slab
        const float* s = sq + b * 256;
        float v = s[lane] + s[64 + lane] + s[128 + lane] + s[192 + lane];
        #pragma unroll
        for (int off = 32; off; off >>= 1) v += __shfl_xor(v, off);
        if (lane == 0) part_sq[b] = v;
    }
}

// ---------------- K3b: final deterministic reduction of partials
__global__ void k_colfin(const float* __restrict__ part, const float* __restrict__ part_sq,
                         float* __restrict__ tS) {
    const int tid = threadIdx.x;
    if (tid < DP) {
        float acc = 0.0f;
        #pragma unroll 8
        for (int b = 0; b < 64; ++b) acc += part[b * DP + tid];
        tS[tid] = acc;
    } else if (tid == DP) {
        float s = 0.0f;
        #pragma unroll
        for (int b = 0; b < 64; ++b) s += part_sq[b];
        tS[DP] = s;
    }
}

// ---------------- K4: greedy FPS loop; single poll wave + sleep backoff
__global__ __launch_bounds__(BTHR, 1) void k_greedy(
    const float* __restrict__ R, const float* __restrict__ sq,
    const float* __restrict__ tS, const float* __restrict__ F,
    unsigned long long* gmax, float* __restrict__ out) {
    __shared__ unsigned long long lmax[WPB];
    __shared__ unsigned sidx_cur;
    __shared__ unsigned sidx[(NS + NBLK - 1) / NBLK];   // 3

    const int tid  = threadIdx.x;
    const int lane = tid & 63;
    const int wid  = tid >> 6;
    const int bid  = blockIdx.x;
    const int g    = bid * BTHR + tid;          // my point id, 0..16383

    // own projected row in registers (32 x float4 = 128 VGPRs)
    float4 rr[32];
    #pragma unroll
    for (int q = 0; q < 32; ++q) rr[q] = *(const float4*)&R[(size_t)g * DP + q * 4];
    const float sqi = sq[g];

    // anchor0 = sqrt(N*sq_i + S - 2*r_i.t)  (common terms preserve ranking)
    float a0 = 0.f, a1 = 0.f, a2 = 0.f, a3 = 0.f;
    #pragma unroll
    for (int q = 0; q < 32; ++q) {
        const float4 t4 = *(const float4*)&tS[q * 4];
        a0 += rr[q].x * t4.x; a1 += rr[q].y * t4.y;
        a2 += rr[q].z * t4.z; a3 += rr[q].w * t4.w;
    }
    const float S = tS[DP];
    float anchor = sqrtf(fmaxf((float)NPTS * sqi + S - 2.0f * ((a0 + a1) + (a2 + a3)), 0.0f));

    for (int k = 0; k < NS; ++k) {
        // key = (bits(anchor)<<32) | (~g): max-key == first-occurrence argmax; never 0
        unsigned long long key =
            ((unsigned long long)__float_as_uint(anchor) << 32) |
            (unsigned long long)(0xFFFFFFFFu - (unsigned)g);
        #pragma unroll
        for (int off = 32; off; off >>= 1) {
            const unsigned long long o = __shfl_xor(key, off);
            key = (o > key) ? o : key;
        }
        if (lane == 0) lmax[wid] = key;
        __syncthreads();

        if (wid == 0) {
            if (lane == 0) {
                unsigned long long bk = lmax[0];
                #pragma unroll
                for (int w = 1; w < WPB; ++w) bk = (lmax[w] > bk) ? lmax[w] : bk;
                __hip_atomic_store(&gmax[(size_t)k * NBLK + bid], bk,
                                   __ATOMIC_RELAXED, __HIP_MEMORY_SCOPE_AGENT);
            }
            // only wave 0 polls: 64 pollers GPU-wide, sleep backoff cuts LLC pressure
            const unsigned long long* gs = &gmax[(size_t)k * NBLK];
            unsigned long long v =
                __hip_atomic_load(&gs[lane], __ATOMIC_RELAXED, __HIP_MEMORY_SCOPE_AGENT);
            while (!__all(v != 0ull)) {
                __builtin_amdgcn_s_sleep(2);
                v = __hip_atomic_load(&gs[lane], __ATOMIC_RELAXED, __HIP_MEMORY_SCOPE_AGENT);
            }
            #pragma unroll
            for (int off = 32; off; off >>= 1) {
                const unsigned long long o = __shfl_xor(v, off);
                v = (o > v) ? o : v;
            }
            if (lane == 0) {
                const unsigned idx = 0xFFFFFFFFu - (unsigned)(v & 0xFFFFFFFFull);
                sidx_cur = idx;
                if ((k & 63) == bid) sidx[k >> 6] = idx;
            }
        }
        __syncthreads();
        const unsigned idx = sidx_cur;

        // anchor = min(anchor, dist(g, idx)); selected row via L1-broadcast loads
        const float sqs = sq[idx];
        const float* rs = &R[(size_t)idx * DP];
        float d0 = 0.f, d1 = 0.f, d2 = 0.f, d3 = 0.f;
        #pragma unroll
        for (int q = 0; q < 32; ++q) {
            const float4 w4 = *(const float4*)&rs[q * 4];
            d0 += rr[q].x * w4.x; d1 += rr[q].y * w4.y;
            d2 += rr[q].z * w4.z; d3 += rr[q].w * w4.w;
        }
        const float d = sqrtf(fmaxf(sqi + sqs - 2.0f * ((d0 + d1) + (d2 + d3)), 0.0f));
        anchor = fminf(anchor, d);

        // loop-carried register pin: rr appears modified -> cannot be
        // rematerialized from R, must stay resident in VGPRs
        #pragma unroll
        for (int q = 0; q < 32; ++q)
            asm volatile("" : "+v"(rr[q].x), "+v"(rr[q].y), "+v"(rr[q].z), "+v"(rr[q].w));
    }

    __syncthreads();
    // gather: block b owns k = b, b+64, b+128 (indices recorded in sidx)
    #pragma unroll
    for (int q = 0; q < 3; ++q) {
        const int k = q * NBLK + bid;
        if (k < NS) {
            const unsigned idx = sidx[q];
            *(float4*)&out[(size_t)k * DIN + tid * 4] =
                *(const float4*)&F[(size_t)idx * DIN + tid * 4];
        }
    }
}

extern "C" void kernel_launch(void* const* d_in, const int* in_sizes, int n_in,
                              void* d_out, int out_size, void* d_ws, size_t ws_size,
                              hipStream_t stream) {
    const float* F = (const float*)d_in[0];   // [16384,1024]
    const float* W = (const float*)d_in[1];   // [1024,128]
    float* out = (float*)d_out;               // [163,1024]

    float* R       = (float*)d_ws;                    // 16384*128 f32 = 8 MiB
    float* sq      = R + (size_t)NPTS * DP;           // 16384 f32
    float* tS      = sq + NPTS;                       // 129 f32 (pad to 132)
    float* part    = tS + 132;                        // 64*128 f32
    float* part_sq = part + 64 * DP;                  // 64 f32
    unsigned long long* gmax = (unsigned long long*)(part_sq + 64);  // NS*NBLK u64

    hipLaunchKernelGGL(k_proj, dim3(NPTS / 32), dim3(256), 0, stream, F, W, R);
    hipLaunchKernelGGL(k_sq, dim3(64), dim3(256), 0, stream, R, sq);
    hipLaunchKernelGGL(k_colpart, dim3(64), dim3(256), 0, stream, R, sq, part, part_sq, gmax);
    hipLaunchKernelGGL(k_colfin, dim3(1), dim3(256), 0, stream, part, part_sq, tS);

    const float* Rc = R; const float* sqc = sq; const float* tSc = tS; const float* Fc = F;
    unsigned long long* gm = gmax; float* op = out;
    void* args[] = { (void*)&Rc, (void*)&sqc, (void*)&tSc, (void*)&Fc,
                     (void*)&gm, (void*)&op };
    hipLaunchCooperativeKernel((const void*)k_greedy, dim3(NBLK), dim3(BTHR),
                               args, 0, stream);
}